// Round 17
// baseline (237.797 us; speedup 1.0000x reference)
//
#include <hip/hip_runtime.h>
#include <hip/hip_bf16.h>

#define CCH 256
#define NPIX 4096
#define NB 8
#define LOG2E 1.4426950408889634f

typedef __attribute__((ext_vector_type(8))) short bf16x8;
typedef __attribute__((ext_vector_type(16))) float f32x16;

typedef __attribute__((address_space(3))) unsigned lds_u32;
typedef const __attribute__((address_space(1))) unsigned glb_u32;
#define GL_LDS16(gp, lp) \
    __builtin_amdgcn_global_load_lds((glb_u32*)(gp), (lds_u32*)(lp), 16, 0, 0)

// one barrier per tile; the stage it drains was issued a full body earlier,
// and the co-resident second block fills the drain stall
#define TBAR() do { __builtin_amdgcn_sched_barrier(0); \
    asm volatile("s_waitcnt vmcnt(0) lgkmcnt(0)" ::: "memory"); \
    __builtin_amdgcn_s_barrier(); __builtin_amdgcn_sched_barrier(0); } while (0)

static __device__ __forceinline__ unsigned pkbf(float a, float b) {
    union { __hip_bfloat16 h[2]; unsigned u; } p;
    p.h[0] = __float2bfloat16(a);
    p.h[1] = __float2bfloat16(b);
    return p.u;
}
static __device__ __forceinline__ unsigned short bf1(float a) {
    union { __hip_bfloat16 h; unsigned short s; } p;
    p.h = __float2bfloat16(a);
    return p.s;
}

// ---------------- Kernel 0: pack W fp32 -> bf16, Wb[320][256] ----------------
__global__ void packw_kernel(const float* __restrict__ Wq,
                             const float* __restrict__ Wk,
                             const float* __restrict__ Wv,
                             unsigned short* __restrict__ Wb) {
    int i4 = blockIdx.x * 256 + threadIdx.x;
    if (i4 >= 20480) return;
    int e = i4 * 4;
    const float* src;
    if (e < 8192)       src = Wq + e;
    else if (e < 16384) src = Wk + (e - 8192);
    else                src = Wv + (e - 16384);
    float4 v = *(const float4*)src;
    uint2 o;
    o.x = pkbf(v.x, v.y);
    o.y = pkbf(v.z, v.w);
    *(uint2*)(Wb + e) = o;
}

// ---------------- Kernel 1: QKV via MFMA (r7/r9-proven, unchanged) ----------
// q [B][N][32] bf16 prescaled log2e; k [B][N][32]; v [B][C][N], pixel bit2<->3.
__global__ __launch_bounds__(320) void qkv_kernel(
    const float* __restrict__ x,
    const unsigned short* __restrict__ Wb,
    const float* __restrict__ bq, const float* __restrict__ bk,
    const float* __restrict__ bv,
    unsigned short* __restrict__ q, unsigned short* __restrict__ k,
    unsigned short* __restrict__ v)
{
    __shared__ __align__(16) unsigned xp[128][36];

    const int t   = threadIdx.x;
    const int b   = blockIdx.x >> 7;
    const int px0 = (blockIdx.x & 127) * 32;

    const float4* gx = (const float4*)x + ((size_t)b * CCH * NPIX + px0) / 4;
    for (int i = t; i < 1024; i += 320) {
        int kp = i >> 3, p4 = i & 7;
        float4 lo = gx[(size_t)(2 * kp) * (NPIX / 4) + p4];
        float4 hi = gx[(size_t)(2 * kp + 1) * (NPIX / 4) + p4];
        uint4 pk4;
        pk4.x = pkbf(lo.x, hi.x);
        pk4.y = pkbf(lo.y, hi.y);
        pk4.z = pkbf(lo.z, hi.z);
        pk4.w = pkbf(lo.w, hi.w);
        *(uint4*)&xp[kp][p4 * 4] = pk4;
    }
    __syncthreads();

    const int w  = t >> 6;
    const int lane = t & 63;
    const int qi = lane & 31, h = lane >> 5;

    f32x16 acc[2];
    #pragma unroll
    for (int rt = 0; rt < 2; ++rt)
        #pragma unroll
        for (int r = 0; r < 16; ++r) acc[rt][r] = 0.f;

    #pragma unroll 4
    for (int ks = 0; ks < 16; ++ks) {
        union { unsigned uw[4]; bf16x8 v8; } xb;
        #pragma unroll
        for (int j = 0; j < 4; ++j) xb.uw[j] = xp[ks * 8 + 4 * h + j][qi];
        #pragma unroll
        for (int rt = 0; rt < 2; ++rt) {
            int row = (2 * w + rt) * 32 + qi;
            bf16x8 af = *(const bf16x8*)(Wb + (size_t)row * 256 + ks * 16 + h * 8);
            acc[rt] = __builtin_amdgcn_mfma_f32_32x32x16_bf16(af, xb.v8, acc[rt], 0, 0, 0);
        }
    }

    const int px = px0 + qi;
    const int pxv = px0 + ((qi & 19) | ((qi & 4) << 1) | ((qi & 8) >> 1)); // bits 2<->3
    #pragma unroll
    for (int rt = 0; rt < 2; ++rt) {
        int tile = 2 * w + rt;
        if (tile < 2) {
            const float* bias = (tile == 0) ? bq : bk;
            unsigned short* outp = (tile == 0) ? q : k;
            float scale = (tile == 0) ? LOG2E : 1.0f;
            #pragma unroll
            for (int rg = 0; rg < 4; ++rg) {
                float vv[4];
                #pragma unroll
                for (int j = 0; j < 4; ++j) {
                    int outd = j + 8 * rg + 4 * h;
                    vv[j] = (acc[rt][4 * rg + j] + bias[outd]) * scale;
                }
                uint2 st;
                st.x = pkbf(vv[0], vv[1]);
                st.y = pkbf(vv[2], vv[3]);
                *(uint2*)(outp + ((size_t)b * NPIX + px) * 32 + 8 * rg + 4 * h) = st;
            }
        } else {
            #pragma unroll
            for (int r = 0; r < 16; ++r) {
                int outd = (r & 3) + 8 * (r >> 2) + 4 * h;
                int grow = (tile - 2) * 32 + outd;
                v[((size_t)b * CCH + grow) * NPIX + pxv] = bf1(acc[rt][r] + bv[grow]);
            }
        }
    }
}

// ---------------- Kernel 2: 4-wave/SIMD symmetric P-in-register attention ----
// 512 thr = 8 waves: wave (qt = w&1, chq = w>>1) owns 32 q x 64 ch.
// Block = 64 q x 256 ch; grid 512 = 2 blocks/CU -> 4 waves/SIMD.
// P in registers (V key-axis pre-permuted); QK+softmax dup x4 (accepted);
// l computed in-lane. LDS = K 8 + V 64 = 72 KB. One TBAR per 64-key tile.
__global__ __launch_bounds__(512, 4) void attn_kernel(
    const unsigned short* __restrict__ qg,
    const unsigned short* __restrict__ kg,
    const unsigned short* __restrict__ vg,
    const float* __restrict__ x,
    const float* __restrict__ gamma,
    float* __restrict__ out)
{
    __shared__ __align__(16) unsigned short Kl[2][64][4][8];    //  8 KB
    __shared__ __align__(16) unsigned short Vl[2][256][8][8];   // 64 KB

    const int t    = threadIdx.x;
    const int b    = blockIdx.x & 7;          // batch == XCD -> K/V L2-resident
    const int n0   = (blockIdx.x >> 3) * 64;  // 0..4032
    const int w    = t >> 6;
    const int lane = t & 63;
    const int qt   = w & 1;                   // q-tile (32 queries)
    const int chq  = w >> 1;                  // ch-quarter (64 channels)
    const int qi = lane & 31, h = lane >> 5;

    // Q fragments
    bf16x8 qf0, qf1;
    {
        const unsigned short* qp = qg + ((size_t)b * NPIX + n0 + qt * 32 + qi) * 32;
        qf0 = *(const bf16x8*)(qp + h * 8);
        qf1 = *(const bf16x8*)(qp + 16 + h * 8);
    }

    // ---- staging: K by threads 0-255 (waves 0-3), V by all 512 ----
    const unsigned short* kg_src =
        kg + ((size_t)b * NPIX + (t >> 2)) * 32 + ((t & 3) ^ ((t >> 2) & 3)) * 8;
    const int vrow = t >> 3;                                  // 0..63
    const unsigned short* vg_src =
        vg + ((size_t)b * CCH + vrow) * NPIX + ((t & 7) ^ (vrow & 7)) * 8;
    char* kl_dst = (char*)Kl + t * 16;                        // valid for t<256
    char* vl_dst = (char*)Vl + t * 16;                        // + buf*32768 + p*8192

    // ---- compute-side LDS read pointers (loop-invariant) ----
    const unsigned short* krd[2][2];
    #pragma unroll
    for (int sub = 0; sub < 2; ++sub)
        #pragma unroll
        for (int s = 0; s < 2; ++s)
            krd[sub][s] = &Kl[0][sub * 32 + qi][(2 * s + h) ^ (qi & 3)][0];
    const unsigned short* vrd[4];
    #pragma unroll
    for (int s = 0; s < 4; ++s)
        vrd[s] = &Vl[0][chq * 64 + qi][(2 * s + h) ^ (qi & 7)][0];  // + ct*2048 + vb

    f32x16 acc[2];
    #pragma unroll
    for (int ct = 0; ct < 2; ++ct)
        #pragma unroll
        for (int r = 0; r < 16; ++r) acc[ct][r] = 0.f;
    float l_run = 0.f;

    auto STAGE = [&](int kt) {                // V: 4 loads all thr; K: 1 load t<256
        const int buf = kt & 1;
        if (t < 256)
            GL_LDS16(kg_src + (size_t)kt * 2048, kl_dst + buf * 4096);
        const unsigned short* s0 = vg_src + kt * 64;
        char* d0 = vl_dst + buf * 32768;
        #pragma unroll
        for (int p = 0; p < 4; ++p)
            GL_LDS16(s0 + (size_t)(64 * p) * NPIX, d0 + p * 8192);
    };

    STAGE(0);
    TBAR();

    #pragma unroll 1
    for (int tt = 0; tt < 64; ++tt) {
        if (tt < 63) STAGE(tt + 1);           // issue early; drains at next TBAR

        const int kb = (tt & 1) * 2048;       // shorts
        const int vb = (tt & 1) * 16384;      // shorts

        // ---- per 32-key sub-tile: QK (2 MFMA) + softmax -> pf, then PV ----
        bf16x8 pf[4];
        #pragma unroll
        for (int sub = 0; sub < 2; ++sub) {
            f32x16 sacc;
            #pragma unroll
            for (int r = 0; r < 16; ++r) sacc[r] = 0.f;
            sacc = __builtin_amdgcn_mfma_f32_32x32x16_bf16(
                *(const bf16x8*)(krd[sub][0] + kb), qf0, sacc, 0, 0, 0);
            sacc = __builtin_amdgcn_mfma_f32_32x32x16_bf16(
                *(const bf16x8*)(krd[sub][1] + kb), qf1, sacc, 0, 0, 0);
            #pragma unroll
            for (int sp = 0; sp < 2; ++sp) {
                union { unsigned uw[4]; bf16x8 v8; } pk;
                float ps = 0.f;
                #pragma unroll
                for (int c = 0; c < 4; ++c) {
                    float ea = exp2f(sacc[8 * sp + 2 * c]);
                    float eb = exp2f(sacc[8 * sp + 2 * c + 1]);
                    ps += ea + eb;
                    pk.uw[c] = pkbf(ea, eb);
                }
                l_run += ps;
                pf[2 * sub + sp] = pk.v8;
            }
        }

        // ---- O^T += V^T . P^T over this wave's 64 channels ----
        __builtin_amdgcn_s_setprio(1);
        #pragma unroll
        for (int ct = 0; ct < 2; ++ct) {
            #pragma unroll
            for (int s = 0; s < 4; ++s) {
                bf16x8 vf = *(const bf16x8*)(vrd[s] + vb + ct * 2048);
                acc[ct] = __builtin_amdgcn_mfma_f32_32x32x16_bf16(vf, pf[s], acc[ct], 0, 0, 0);
            }
        }
        __builtin_amdgcn_s_setprio(0);

        TBAR();                               // drains STAGE(tt+1)
    }

    // ---- epilogue: out = gamma * O / l + x ----
    float l = l_run + __shfl_xor(l_run, 32, 64);
    const float rs = gamma[0] / l;
    #pragma unroll
    for (int ct = 0; ct < 2; ++ct) {
        #pragma unroll
        for (int r = 0; r < 16; ++r) {
            int c = chq * 64 + ct * 32 + (r & 3) + 8 * (r >> 2) + 4 * h;
            size_t off = ((size_t)b * CCH + c) * NPIX + n0 + qt * 32 + qi;
            out[off] = rs * acc[ct][r] + x[off];
        }
    }
}

extern "C" void kernel_launch(void* const* d_in, const int* in_sizes, int n_in,
                              void* d_out, int out_size, void* d_ws, size_t ws_size,
                              hipStream_t stream) {
    const float* x     = (const float*)d_in[0];
    const float* Wq    = (const float*)d_in[1];
    const float* bq    = (const float*)d_in[2];
    const float* Wk    = (const float*)d_in[3];
    const float* bk    = (const float*)d_in[4];
    const float* Wv    = (const float*)d_in[5];
    const float* bv    = (const float*)d_in[6];
    const float* gamma = (const float*)d_in[7];
    float* out = (float*)d_out;

    unsigned short* Wb = (unsigned short*)d_ws;
    unsigned short* qw = Wb + 320 * 256;
    unsigned short* kw = qw + (size_t)NB * NPIX * 32;
    unsigned short* vw = kw + (size_t)NB * NPIX * 32;

    packw_kernel<<<dim3(80), dim3(256), 0, stream>>>(Wq, Wk, Wv, Wb);
    qkv_kernel<<<dim3(NB * (NPIX / 32)), dim3(320), 0, stream>>>(
        x, Wb, bq, bk, bv, qw, kw, vw);
    attn_kernel<<<dim3(512), dim3(512), 0, stream>>>(
        qw, kw, vw, x, gamma, out);
}

// Round 18
// 138.793 us; speedup vs baseline: 1.7133x; 1.7133x over previous
//
#include <hip/hip_runtime.h>
#include <hip/hip_bf16.h>

#define CCH 256
#define NPIX 4096
#define NB 8
#define LOG2E 1.4426950408889634f

typedef __attribute__((ext_vector_type(8))) short bf16x8;
typedef __attribute__((ext_vector_type(16))) float f32x16;

typedef __attribute__((address_space(3))) unsigned lds_u32;
typedef const __attribute__((address_space(1))) unsigned glb_u32;
#define GL_LDS16(gp, lp) \
    __builtin_amdgcn_global_load_lds((glb_u32*)(gp), (lds_u32*)(lp), 16, 0, 0)

// producer barrier, counted vmcnt; NO pre-barrier sched fence (m141 lesson) --
// the asm "memory" clobber orders memory ops; post-fence stops post-barrier
// loads from hoisting above the rendezvous.
#define PBAR_PROD(N) do { \
    asm volatile("s_waitcnt vmcnt(" #N ") lgkmcnt(0)" ::: "memory"); \
    __builtin_amdgcn_s_barrier(); __builtin_amdgcn_sched_barrier(0); } while (0)
// consumer barrier: reads already consumed by MFMAs (data-dep waitcnt)
#define PBAR_CONS() do { \
    __builtin_amdgcn_s_barrier(); __builtin_amdgcn_sched_barrier(0); } while (0)

static __device__ __forceinline__ unsigned pkbf(float a, float b) {
    union { __hip_bfloat16 h[2]; unsigned u; } p;
    p.h[0] = __float2bfloat16(a);
    p.h[1] = __float2bfloat16(b);
    return p.u;
}
static __device__ __forceinline__ unsigned short bf1(float a) {
    union { __hip_bfloat16 h; unsigned short s; } p;
    p.h = __float2bfloat16(a);
    return p.s;
}

// ---------------- Kernel 0: pack W fp32 -> bf16, Wb[320][256] ----------------
__global__ void packw_kernel(const float* __restrict__ Wq,
                             const float* __restrict__ Wk,
                             const float* __restrict__ Wv,
                             unsigned short* __restrict__ Wb) {
    int i4 = blockIdx.x * 256 + threadIdx.x;
    if (i4 >= 20480) return;
    int e = i4 * 4;
    const float* src;
    if (e < 8192)       src = Wq + e;
    else if (e < 16384) src = Wk + (e - 8192);
    else                src = Wv + (e - 16384);
    float4 v = *(const float4*)src;
    uint2 o;
    o.x = pkbf(v.x, v.y);
    o.y = pkbf(v.z, v.w);
    *(uint2*)(Wb + e) = o;
}

// ---------------- Kernel 1: QKV via MFMA (r7/r9-proven, unchanged) ----------
// q [B][N][32] bf16 prescaled log2e; k [B][N][32]; v [B][C][N], pixel bit2<->3.
__global__ __launch_bounds__(320) void qkv_kernel(
    const float* __restrict__ x,
    const unsigned short* __restrict__ Wb,
    const float* __restrict__ bq, const float* __restrict__ bk,
    const float* __restrict__ bv,
    unsigned short* __restrict__ q, unsigned short* __restrict__ k,
    unsigned short* __restrict__ v)
{
    __shared__ __align__(16) unsigned xp[128][36];

    const int t   = threadIdx.x;
    const int b   = blockIdx.x >> 7;
    const int px0 = (blockIdx.x & 127) * 32;

    const float4* gx = (const float4*)x + ((size_t)b * CCH * NPIX + px0) / 4;
    for (int i = t; i < 1024; i += 320) {
        int kp = i >> 3, p4 = i & 7;
        float4 lo = gx[(size_t)(2 * kp) * (NPIX / 4) + p4];
        float4 hi = gx[(size_t)(2 * kp + 1) * (NPIX / 4) + p4];
        uint4 pk4;
        pk4.x = pkbf(lo.x, hi.x);
        pk4.y = pkbf(lo.y, hi.y);
        pk4.z = pkbf(lo.z, hi.z);
        pk4.w = pkbf(lo.w, hi.w);
        *(uint4*)&xp[kp][p4 * 4] = pk4;
    }
    __syncthreads();

    const int w  = t >> 6;
    const int lane = t & 63;
    const int qi = lane & 31, h = lane >> 5;

    f32x16 acc[2];
    #pragma unroll
    for (int rt = 0; rt < 2; ++rt)
        #pragma unroll
        for (int r = 0; r < 16; ++r) acc[rt][r] = 0.f;

    #pragma unroll 4
    for (int ks = 0; ks < 16; ++ks) {
        union { unsigned uw[4]; bf16x8 v8; } xb;
        #pragma unroll
        for (int j = 0; j < 4; ++j) xb.uw[j] = xp[ks * 8 + 4 * h + j][qi];
        #pragma unroll
        for (int rt = 0; rt < 2; ++rt) {
            int row = (2 * w + rt) * 32 + qi;
            bf16x8 af = *(const bf16x8*)(Wb + (size_t)row * 256 + ks * 16 + h * 8);
            acc[rt] = __builtin_amdgcn_mfma_f32_32x32x16_bf16(af, xb.v8, acc[rt], 0, 0, 0);
        }
    }

    const int px = px0 + qi;
    const int pxv = px0 + ((qi & 19) | ((qi & 4) << 1) | ((qi & 8) >> 1)); // bits 2<->3
    #pragma unroll
    for (int rt = 0; rt < 2; ++rt) {
        int tile = 2 * w + rt;
        if (tile < 2) {
            const float* bias = (tile == 0) ? bq : bk;
            unsigned short* outp = (tile == 0) ? q : k;
            float scale = (tile == 0) ? LOG2E : 1.0f;
            #pragma unroll
            for (int rg = 0; rg < 4; ++rg) {
                float vv[4];
                #pragma unroll
                for (int j = 0; j < 4; ++j) {
                    int outd = j + 8 * rg + 4 * h;
                    vv[j] = (acc[rt][4 * rg + j] + bias[outd]) * scale;
                }
                uint2 st;
                st.x = pkbf(vv[0], vv[1]);
                st.y = pkbf(vv[2], vv[3]);
                *(uint2*)(outp + ((size_t)b * NPIX + px) * 32 + 8 * rg + 4 * h) = st;
            }
        } else {
            #pragma unroll
            for (int r = 0; r < 16; ++r) {
                int outd = (r & 3) + 8 * (r >> 2) + 4 * h;
                int grow = (tile - 2) * 32 + outd;
                v[((size_t)b * CCH + grow) * NPIX + pxv] = bf1(acc[rt][r] + bv[grow]);
            }
        }
    }
}

// ---------------- Kernel 2: p/c attention, counted vmcnt, NO setprio --------
// 512 thr, grid 256 (1 blk/CU). Producers w0-3 (q-tile each): stage K/V 2 tiles
// ahead (V,K triple-buffered), QK^T+softmax -> Pt (dbuf). Consumers w4-7
// (64ch each): pure LDS+MFMA PV. Steady-state barrier waits vmcnt(9).
__global__ __launch_bounds__(512, 2) void attn_kernel(
    const unsigned short* __restrict__ qg,
    const unsigned short* __restrict__ kg,
    const unsigned short* __restrict__ vg,
    const float* __restrict__ x,
    const float* __restrict__ gamma,
    float* __restrict__ out)
{
    __shared__ __align__(16) unsigned short Kl[3][64][4][8];    // 12 KB
    __shared__ __align__(16) unsigned short Vl[3][256][8][8];   // 96 KB
    __shared__ __align__(16) unsigned short Pt[2][128][64];     // 32 KB
    __shared__ float Lx[128];

    const int t    = threadIdx.x;
    const int b    = blockIdx.x & 7;          // batch == XCD -> K/V L2-resident
    const int n0   = (blockIdx.x >> 3) * 128;
    const int w    = t >> 6;
    const int lane = t & 63;
    const int qi = lane & 31, h = lane >> 5;

    int po[4];
    #pragma unroll
    for (int s = 0; s < 4; ++s) po[s] = ((2 * s + h) ^ (qi & 7)) * 8;

    if (w < 4) {
        // =============== PRODUCER (q-tile qt = w) ===============
        const int qt = w;
        bf16x8 qf0, qf1;
        {
            const unsigned short* qp = qg + ((size_t)b * NPIX + n0 + qt * 32 + qi) * 32;
            qf0 = *(const bf16x8*)(qp + h * 8);
            qf1 = *(const bf16x8*)(qp + 16 + h * 8);
        }
        const int srow = t >> 2;                                  // K row 0..63
        const unsigned short* kg_src =
            kg + ((size_t)b * NPIX + srow) * 32 + ((t & 3) ^ (srow & 3)) * 8;
        const int vrow = t >> 3;                                  // V row 0..31
        const unsigned short* vg_src =
            vg + ((size_t)b * CCH + vrow) * NPIX + ((t & 7) ^ (vrow & 7)) * 8;
        char* kl_dst = (char*)Kl + t * 16;                        // + kbuf*4096
        char* vl_dst = (char*)Vl + t * 16;                        // + vbuf*32768 + p*4096

        const unsigned short* krd[2][2];
        #pragma unroll
        for (int sub = 0; sub < 2; ++sub)
            #pragma unroll
            for (int s = 0; s < 2; ++s)
                krd[sub][s] = &Kl[0][sub * 32 + qi][(2 * s + h) ^ (qi & 3)][0];
        unsigned short* pw = &Pt[0][32 * qt + qi][0];

        float l_run = 0.f;

        auto STAGEV = [&](int kt, int buf) {  // 8 loads -> Vl[buf]
            const unsigned short* s0 = vg_src + kt * 64;
            char* d0 = vl_dst + buf * 32768;
            #pragma unroll
            for (int p = 0; p < 8; ++p)
                GL_LDS16(s0 + (size_t)(32 * p) * NPIX, d0 + p * 4096);
        };
        auto STAGEK = [&](int kt, int buf) {  // 1 load -> Kl[buf]
            GL_LDS16(kg_src + (size_t)kt * 2048, kl_dst + buf * 4096);
        };
        auto QKSM = [&](int kbuf, int pbuf) {
            const int kb = kbuf * 2048;       // shorts
            f32x16 s0, s1;
            #pragma unroll
            for (int r = 0; r < 16; ++r) { s0[r] = 0.f; s1[r] = 0.f; }
            s0 = __builtin_amdgcn_mfma_f32_32x32x16_bf16(*(const bf16x8*)(krd[0][0] + kb), qf0, s0, 0, 0, 0);
            s0 = __builtin_amdgcn_mfma_f32_32x32x16_bf16(*(const bf16x8*)(krd[0][1] + kb), qf1, s0, 0, 0, 0);
            s1 = __builtin_amdgcn_mfma_f32_32x32x16_bf16(*(const bf16x8*)(krd[1][0] + kb), qf0, s1, 0, 0, 0);
            s1 = __builtin_amdgcn_mfma_f32_32x32x16_bf16(*(const bf16x8*)(krd[1][1] + kb), qf1, s1, 0, 0, 0);
            unsigned short* pwb = pw + pbuf * 8192;
            #pragma unroll
            for (int sub = 0; sub < 2; ++sub) {
                const f32x16& sv2 = sub ? s1 : s0;
                #pragma unroll
                for (int mh = 0; mh < 2; ++mh) {
                    union { unsigned uw[4]; bf16x8 v8; } pk;
                    float ps = 0.f;
                    #pragma unroll
                    for (int c = 0; c < 4; ++c) {
                        float ea = exp2f(sv2[8 * mh + 2 * c]);
                        float eb = exp2f(sv2[8 * mh + 2 * c + 1]);
                        ps += ea + eb;
                        pk.uw[c] = pkbf(ea, eb);
                    }
                    l_run += ps;
                    *(bf16x8*)(pwb + po[2 * sub + mh]) = pk.v8;
                }
            }
        };

        // prologue: V0,K0,V1,K1,K2 issued (19); drain all but newest 10
        STAGEV(0, 0); STAGEK(0, 0);
        STAGEV(1, 1); STAGEK(1, 1); STAGEK(2, 2);
        PBAR_PROD(10);                        // V0,K0 (and q) landed
        QKSM(0, 0);                           // P(0) -> Pt[0]
        PBAR_PROD(1);                         // V1,K1 landed; keep K2 in flight

        int sv = 2, sk = 0, kq = 1;           // V-stage buf, K-stage buf, K-read buf
        #pragma unroll 1
        for (int tt = 0; tt <= 60; ++tt) {
            STAGEV(tt + 2, sv);
            STAGEK(tt + 3, sk);
            QKSM(kq, (tt + 1) & 1);           // P(tt+1)
            PBAR_PROD(9);                     // keep newest V[8]+K[1]
            sv = (sv == 2) ? 0 : sv + 1;
            sk = (sk == 2) ? 0 : sk + 1;
            kq = (kq == 2) ? 0 : kq + 1;
        }
        // tt = 61: stage V(63) only   (sv == 0 here: (2+61)%3 == 0)
        STAGEV(63, 0);
        QKSM(kq, 0);                          // P(62) -> Pt[0], kq == 2
        PBAR_PROD(8);                         // K(63) landed; keep V(63)[8]
        // tt = 62
        QKSM(0, 1);                           // P(63) -> Pt[1], K(63) in buf 0
        PBAR_PROD(0);                         // V(63) landed
        // tt = 63: publish l
        {
            float lt = l_run + __shfl_xor(l_run, 32, 64);
            if (lane < 32) Lx[32 * qt + lane] = lt;
        }
        PBAR_PROD(0);
    } else {
        // =============== CONSUMER (ch-quarter cw = w-4), pure LDS+MFMA ========
        const int cw = w - 4;
        const unsigned short* vrd[2][4];
        #pragma unroll
        for (int ct = 0; ct < 2; ++ct)
            #pragma unroll
            for (int s = 0; s < 4; ++s)
                vrd[ct][s] = &Vl[0][64 * cw + 32 * ct + qi][(2 * s + h) ^ (qi & 7)][0];
        const unsigned short* prd = &Pt[0][qi][0];

        f32x16 acc[2][4];
        #pragma unroll
        for (int ct = 0; ct < 2; ++ct)
            #pragma unroll
            for (int qt = 0; qt < 4; ++qt)
                #pragma unroll
                for (int r = 0; r < 16; ++r) acc[ct][qt][r] = 0.f;

        PBAR_CONS();
        PBAR_CONS();
        int cv = 0;                           // V(tt) buffer = tt % 3
        #pragma unroll 1
        for (int tt = 0; tt < 64; ++tt) {
            const int vb = cv * 16384;        // shorts
            const int pb = (tt & 1) * 8192;   // shorts
            bf16x8 vf[2][4];
            #pragma unroll
            for (int ct = 0; ct < 2; ++ct)
                #pragma unroll
                for (int s = 0; s < 4; ++s)
                    vf[ct][s] = *(const bf16x8*)(vrd[ct][s] + vb);
            #pragma unroll
            for (int qt = 0; qt < 4; ++qt) {
                bf16x8 pf[4];
                #pragma unroll
                for (int s = 0; s < 4; ++s)
                    pf[s] = *(const bf16x8*)(prd + pb + qt * 2048 + po[s]);
                #pragma unroll
                for (int ct = 0; ct < 2; ++ct)
                    #pragma unroll
                    for (int s = 0; s < 4; ++s)
                        acc[ct][qt] = __builtin_amdgcn_mfma_f32_32x32x16_bf16(
                            vf[ct][s], pf[s], acc[ct][qt], 0, 0, 0);
            }
            PBAR_CONS();
            cv = (cv == 2) ? 0 : cv + 1;
        }

        // epilogue: out = gamma * O / l + x
        const float g = gamma[0];
        float rsl[4];
        #pragma unroll
        for (int qt = 0; qt < 4; ++qt) rsl[qt] = g / Lx[32 * qt + qi];
        #pragma unroll
        for (int ct = 0; ct < 2; ++ct) {
            #pragma unroll
            for (int qt = 0; qt < 4; ++qt) {
                #pragma unroll
                for (int r = 0; r < 16; ++r) {
                    int c = 64 * cw + 32 * ct + (r & 3) + 8 * (r >> 2) + 4 * h;
                    size_t off = ((size_t)b * CCH + c) * NPIX + n0 + 32 * qt + qi;
                    out[off] = rsl[qt] * acc[ct][qt][r] + x[off];
                }
            }
        }
    }
}

extern "C" void kernel_launch(void* const* d_in, const int* in_sizes, int n_in,
                              void* d_out, int out_size, void* d_ws, size_t ws_size,
                              hipStream_t stream) {
    const float* x     = (const float*)d_in[0];
    const float* Wq    = (const float*)d_in[1];
    const float* bq    = (const float*)d_in[2];
    const float* Wk    = (const float*)d_in[3];
    const float* bk    = (const float*)d_in[4];
    const float* Wv    = (const float*)d_in[5];
    const float* bv    = (const float*)d_in[6];
    const float* gamma = (const float*)d_in[7];
    float* out = (float*)d_out;

    unsigned short* Wb = (unsigned short*)d_ws;
    unsigned short* qw = Wb + 320 * 256;
    unsigned short* kw = qw + (size_t)NB * NPIX * 32;
    unsigned short* vw = kw + (size_t)NB * NPIX * 32;

    packw_kernel<<<dim3(80), dim3(256), 0, stream>>>(Wq, Wk, Wv, Wb);
    qkv_kernel<<<dim3(NB * (NPIX / 32)), dim3(320), 0, stream>>>(
        x, Wb, bq, bk, bv, qw, kw, vw);
    attn_kernel<<<dim3(256), dim3(512), 0, stream>>>(
        qw, kw, vw, x, gamma, out);
}